// Round 4
// baseline (375.464 us; speedup 1.0000x reference)
//
#include <hip/hip_runtime.h>

#define FEAT 256
#define HID 128
#define NKEYS 2

typedef __bf16 bf16x8 __attribute__((ext_vector_type(8)));
typedef float f32x16 __attribute__((ext_vector_type(16)));

union Frag {
    bf16x8 v;
    unsigned u[4];
    uint4 q;
};

// pack two f32 -> two bf16 (round-half-up) in one v_perm
__device__ __forceinline__ unsigned pack_bf16_2(float f0, float f1) {
    unsigned u0 = __float_as_uint(f0) + 0x8000u;
    unsigned u1 = __float_as_uint(f1) + 0x8000u;
    return __builtin_amdgcn_perm(u1, u0, 0x07060302u);
}

// shifted softplus: softplus(x) - ln2
__device__ __forceinline__ float ssp(float x) {
    float sp = __logf(1.0f + __expf(x));
    sp = (x > 15.0f) ? x : sp;
    return sp - 0.69314718056f;
}

// largest m with off[m] <= g  (off[0]=0, off sorted, n_mols+1 entries)
__device__ __forceinline__ int find_mol(const int* off, int n_mols, int g) {
    int lo = 0, hi = n_mols;
    while (hi - lo > 1) {
        int mid = (lo + hi) >> 1;
        if (off[mid] <= g) lo = mid; else hi = mid;
    }
    return lo;
}

// async global -> LDS, 16B per lane; lptr must be wave-uniform (HW adds lane*16)
__device__ __forceinline__ void gload_lds16(const float* g, void* l) {
    __builtin_amdgcn_global_load_lds(
        (const __attribute__((address_space(1))) unsigned int*)g,
        (__attribute__((address_space(3))) unsigned int*)l,
        16, 0, 0);
}

// Block 0: prefix-scan num_atoms (int32, falling back to int64 if the int32
// interpretation doesn't sum to n_atoms) + zero d_out (parallel scans).
// Blocks 1..256: pack W1 -> Bp bf16, layout Bp[c][k] (c = key*HID + j).
__global__ void prep_kernel(const void* __restrict__ num_atoms_raw,
                            const float* __restrict__ W1,
                            int n_mols, int n_atoms,
                            int* __restrict__ off,
                            unsigned short* __restrict__ Bp,
                            float* __restrict__ out, int out_n) {
    if (blockIdx.x > 0) {
        int idx = (blockIdx.x - 1) * 256 + threadIdx.x;   // 0..65535
        int c = idx >> 8;
        int k = idx & 255;
        int key = c >> 7, j = c & 127;
        float f = W1[(size_t)key * FEAT * HID + (size_t)k * HID + j];
        unsigned u = __float_as_uint(f);
        unsigned r = (u + 0x7FFFu + ((u >> 16) & 1u)) >> 16;   // RNE to bf16
        Bp[(size_t)c * FEAT + k] = (unsigned short)r;
        return;
    }
    for (int i = threadIdx.x; i < out_n; i += 256) out[i] = 0.0f;

    __shared__ long long tsum[256];
    __shared__ int csum[256];
    int tid = threadIdx.x;
    const int* a32 = (const int*)num_atoms_raw;
    const long long* a64 = (const long long*)num_atoms_raw;
    int chunk = (n_mols + 255) >> 8;
    int lo = tid * chunk;
    if (lo > n_mols) lo = n_mols;
    int hi = lo + chunk;
    if (hi > n_mols) hi = n_mols;

    long long s32 = 0;
    for (int i = lo; i < hi; ++i) s32 += (long long)a32[i];
    tsum[tid] = s32;
    __syncthreads();
    #pragma unroll
    for (int d = 128; d > 0; d >>= 1) {
        if (tid < d) tsum[tid] += tsum[tid + d];
        __syncthreads();
    }
    int mode = (tsum[0] == (long long)n_atoms) ? 0 : 1;
    long long s = s32;
    if (mode) {
        s = 0;
        for (int i = lo; i < hi; ++i) s += a64[i];
    }
    int v = (int)s;
    csum[tid] = v;
    __syncthreads();
    #pragma unroll
    for (int d = 1; d < 256; d <<= 1) {
        int t = (tid >= d) ? csum[tid - d] : 0;
        __syncthreads();
        csum[tid] += t;
        __syncthreads();
    }
    int run = csum[tid] - v;
    for (int i = lo; i < hi; ++i) {
        off[i] = run;
        run += mode ? (int)a64[i] : a32[i];
    }
    if (hi >= n_mols) off[n_mols] = run;
}

// Persistent-block fused GEMM + MLP epilogue + segment-sum.
// 512 threads = 8 waves; wave w owns output cols [w*32, w*32+32) (key = w>>2).
// Tile = 64 rows; K in 4 chunks of 64. Chunk (64x64 fp32 = 16KB) DMA'd via
// global_load_lds, 2-deep double buffer: B frags load FIRST (counted vmcnt
// leaves DMAs in flight), then next chunk's DMA issues, then compute, one
// __syncthreads per chunk. Epilogue OUT of the unrolled loop, all epilogue
// LDS single-buffered (each reuse is >=4 barriers apart) -- round-3's spill
// (35MB scratch writes) came from the epilogue+dbuf knot inside the chunk loop.
__global__ __launch_bounds__(512, 4)
void gemm_fused(const float* __restrict__ A,
                const unsigned short* __restrict__ Bp,
                const float* __restrict__ b1,
                const float* __restrict__ W2,
                const float* __restrict__ b2,
                const int* __restrict__ off,
                float* __restrict__ out,
                int n_atoms, int n_mols, int ntiles, int stride) {
    __shared__ uint4  ldsA[2][1024];      // 2 x 16KB A-chunk (64 rows x 16 units)
    __shared__ int    offlds[2048];       // 8KB prefix offsets
    __shared__ float  part[8][64];        // [wave][row]
    __shared__ int    rowmol[64];
    __shared__ float  molacc[NKEYS][4];

    const int tid  = threadIdx.x;
    const int lane = tid & 63;
    const int wid  = tid >> 6;            // 0..7
    const int l31  = lane & 31;
    const int half = lane >> 5;

    const bool lds_ok = (n_mols + 1) <= 2048;
    if (lds_ok) ((int4*)offlds)[tid] = ((const int4*)off)[tid];
    if (tid < NKEYS * 4) molacc[tid >> 2][tid & 3] = 0.0f;

    const int c0 = wid * 32 + l31;
    const unsigned short* bb = Bp + (size_t)c0 * FEAT + half * 8;
    const float b1c  = b1[c0];
    const float w2c  = W2[c0];
    const float b2k0 = b2[0], b2k1 = b2[1];
    const int rB = l31 + 32;
    const int x  = l31 & 15;

    // stage chunk (tile, c) into ldsA[buf]: per thread 2 DMAs of 16B.
    // LDS unit (row r, u) holds source unit u ^ (r&15) (involution; the read
    // side applies the same XOR). DMA dest is linear (rule #21).
    auto stage = [&](int tile, int c, int buf) {
        const int m0s = tile * 64;
        #pragma unroll
        for (int i = 0; i < 2; ++i) {
            const int pos = wid * 128 + i * 64;        // wave-uniform dest unit
            const int r   = (pos >> 4) + (lane >> 4);  // this lane's row
            const int u   = (lane & 15) ^ (r & 15);    // inverse-swizzled src
            int gr = m0s + r;
            if (gr > n_atoms - 1) gr = n_atoms - 1;
            gload_lds16(A + (size_t)gr * FEAT + c * 64 + u * 4,
                        (void*)(&ldsA[buf][pos]));
        }
    };

    int t = blockIdx.x;
    int cur = 0;
    stage(t, 0, 0);
    __syncthreads();

    for (; t < ntiles; t += stride) {
        const int m0 = t * 64;
        f32x16 acc0 = 0.0f, acc1 = 0.0f;

        #pragma unroll
        for (int c = 0; c < 4; ++c) {
            // B frags FIRST: their vmcnt wait then counts past the newer DMAs
            Frag bw[4];
            #pragma unroll
            for (int j = 0; j < 4; ++j)
                bw[j].q = *(const uint4*)(bb + c * 64 + j * 16);
            __builtin_amdgcn_sched_barrier(0);

            const bool last = (c == 3) && (t + stride >= ntiles);
            if (!last) stage((c < 3) ? t : (t + stride), (c + 1) & 3, cur ^ 1);

            // per-tile row->mol map, one search per 8 threads (spread over waves)
            if (c == 0 && (tid & 7) == 0) {
                int r = tid >> 3;
                int gm = m0 + r;
                if (gm > n_atoms - 1) gm = n_atoms - 1;
                rowmol[r] = lds_ok ? find_mol(offlds, n_mols, gm)
                                   : find_mol(off, n_mols, gm);
            }

            const uint4* lbuf = ldsA[cur];
            #pragma unroll
            for (int ks = 0; ks < 4; ++ks) {
                const int us = (ks * 4 + half * 2) ^ x;
                uint4 lo0 = lbuf[l31 * 16 + us];
                uint4 hi0 = lbuf[l31 * 16 + (us ^ 1)];
                uint4 lo1 = lbuf[rB  * 16 + us];
                uint4 hi1 = lbuf[rB  * 16 + (us ^ 1)];
                const float4 fl0 = *(const float4*)&lo0;
                const float4 fh0 = *(const float4*)&hi0;
                const float4 fl1 = *(const float4*)&lo1;
                const float4 fh1 = *(const float4*)&hi1;
                Frag a0, a1;
                a0.u[0] = pack_bf16_2(fl0.x, fl0.y);
                a0.u[1] = pack_bf16_2(fl0.z, fl0.w);
                a0.u[2] = pack_bf16_2(fh0.x, fh0.y);
                a0.u[3] = pack_bf16_2(fh0.z, fh0.w);
                a1.u[0] = pack_bf16_2(fl1.x, fl1.y);
                a1.u[1] = pack_bf16_2(fl1.z, fl1.w);
                a1.u[2] = pack_bf16_2(fh1.x, fh1.y);
                a1.u[3] = pack_bf16_2(fh1.z, fh1.w);
                acc0 = __builtin_amdgcn_mfma_f32_32x32x16_bf16(a0.v, bw[ks].v, acc0, 0, 0, 0);
                acc1 = __builtin_amdgcn_mfma_f32_32x32x16_bf16(a1.v, bw[ks].v, acc1, 0, 0, 0);
            }

            __syncthreads();
            cur ^= 1;
        }

        // ---- epilogue (once per tile): act + .W2, reduce 32 cols per row
        #pragma unroll
        for (int rt = 0; rt < 2; ++rt) {
            const f32x16& Ac = rt ? acc1 : acc0;
            #pragma unroll
            for (int r = 0; r < 16; ++r) {
                float v = ssp(Ac[r] + b1c) * w2c;
                v += __shfl_xor(v, 1);
                v += __shfl_xor(v, 2);
                v += __shfl_xor(v, 4);
                v += __shfl_xor(v, 8);
                v += __shfl_xor(v, 16);
                if (l31 == r) {
                    int row = rt * 32 + (r & 3) + 8 * (r >> 2) + 4 * half;
                    part[wid][row] = v;
                }
            }
        }
        __syncthreads();

        if (tid < NKEYS * 64) {
            int k = tid >> 6, r = tid & 63;
            int gm = m0 + r;
            if (gm < n_atoms) {
                float val = part[4 * k][r] + part[4 * k + 1][r]
                          + part[4 * k + 2][r] + part[4 * k + 3][r]
                          + (k ? b2k1 : b2k0);
                int mol = rowmol[r];
                int ml  = mol - rowmol[0];
                if (ml < 4) atomicAdd(&molacc[k][ml], val);
                else        atomicAdd(&out[(size_t)k * n_mols + mol], val);
            }
        }
        __syncthreads();

        if (tid < NKEYS * 4) {
            int k = tid >> 2, ml = tid & 3;
            int mol = rowmol[0] + ml;
            if (mol < n_mols) {
                float v = molacc[k][ml];
                if (v != 0.0f) atomicAdd(&out[(size_t)k * n_mols + mol], v);
                molacc[k][ml] = 0.0f;
            }
        }
        // no barrier needed here: next write to molacc/rowmol/part is >=4
        // barriers away (chunk loop), and rowmol[0]/molacc writers are wave 0
        // which executes the flush above first in program order.
    }
}

extern "C" void kernel_launch(void* const* d_in, const int* in_sizes, int n_in,
                              void* d_out, int out_size, void* d_ws, size_t ws_size,
                              hipStream_t stream) {
    const float* s_i      = (const float*)d_in[0];
    // d_in[1] = xyz: unused by the reference output
    const void*  num_atoms = d_in[2];
    const float* W1 = (const float*)d_in[3];
    const float* b1 = (const float*)d_in[4];
    const float* W2 = (const float*)d_in[5];
    const float* b2 = (const float*)d_in[6];
    int n_atoms = in_sizes[0] / FEAT;
    int n_mols  = in_sizes[2];
    float* out = (float*)d_out;

    int* off = (int*)d_ws;
    size_t off_bytes = (((size_t)(n_mols + 1) * 4) + 255) & ~(size_t)255;
    if (off_bytes < 8192) off_bytes = 8192;   // gemm_fused reads 8KB of off
    unsigned short* Bp = (unsigned short*)((char*)d_ws + off_bytes);

    int pack_blocks = (NKEYS * HID * FEAT) / 256;   // 256
    prep_kernel<<<1 + pack_blocks, 256, 0, stream>>>(num_atoms, W1, n_mols, n_atoms,
                                                     off, Bp, out, out_size);

    int ntiles  = (n_atoms + 63) / 64;
    int nblocks = ntiles < 512 ? ntiles : 512;
    gemm_fused<<<nblocks, 512, 0, stream>>>(s_i, Bp, b1, W2, b2, off, out,
                                            n_atoms, n_mols, ntiles, nblocks);
}

// Round 6
// 349.069 us; speedup vs baseline: 1.0756x; 1.0756x over previous
//
#include <hip/hip_runtime.h>

#define FEAT 256
#define HID 128
#define NKEYS 2

typedef __bf16 bf16x8 __attribute__((ext_vector_type(8)));
typedef float f32x16 __attribute__((ext_vector_type(16)));

union Frag {
    bf16x8 v;
    unsigned u[4];
    uint4 q;
};

// pack two f32 -> two bf16 (round-half-up) in one v_perm
__device__ __forceinline__ unsigned pack_bf16_2(float f0, float f1) {
    unsigned u0 = __float_as_uint(f0) + 0x8000u;
    unsigned u1 = __float_as_uint(f1) + 0x8000u;
    return __builtin_amdgcn_perm(u1, u0, 0x07060302u);
}

// shifted softplus: softplus(x) - ln2
__device__ __forceinline__ float ssp(float x) {
    float sp = __logf(1.0f + __expf(x));
    sp = (x > 15.0f) ? x : sp;
    return sp - 0.69314718056f;
}

// largest m with off[m] <= g  (off[0]=0, off sorted, n_mols+1 entries)
__device__ __forceinline__ int find_mol(const int* off, int n_mols, int g) {
    int lo = 0, hi = n_mols;
    while (hi - lo > 1) {
        int mid = (lo + hi) >> 1;
        if (off[mid] <= g) lo = mid; else hi = mid;
    }
    return lo;
}

// async global -> LDS, 16B per lane; lptr must be wave-uniform (HW adds lane*16)
__device__ __forceinline__ void gload_lds16(const float* g, void* l) {
    __builtin_amdgcn_global_load_lds(
        (const __attribute__((address_space(1))) unsigned int*)g,
        (__attribute__((address_space(3))) unsigned int*)l,
        16, 0, 0);
}

// raw workgroup barrier: NO vmcnt drain (keeps global_load_lds DMAs in flight).
__device__ __forceinline__ void bar_raw() {
    __builtin_amdgcn_sched_barrier(0);
    __builtin_amdgcn_s_barrier();
    __builtin_amdgcn_sched_barrier(0);
}
// barrier that publishes/retires LDS ops (lgkm drain only; vmem stays in flight)
__device__ __forceinline__ void bar_lds() {
    __builtin_amdgcn_sched_barrier(0);
    asm volatile("s_waitcnt lgkmcnt(0)" ::: "memory");
    __builtin_amdgcn_s_barrier();
    __builtin_amdgcn_sched_barrier(0);
}

// Block 0: prefix-scan num_atoms (int32, falling back to int64 if the int32
// interpretation doesn't sum to n_atoms) + zero d_out (parallel scans).
// Blocks 1..256: pack W1 -> Bp bf16, layout Bp[c][k] (c = key*HID + j).
__global__ void prep_kernel(const void* __restrict__ num_atoms_raw,
                            const float* __restrict__ W1,
                            int n_mols, int n_atoms,
                            int* __restrict__ off,
                            unsigned short* __restrict__ Bp,
                            float* __restrict__ out, int out_n) {
    if (blockIdx.x > 0) {
        int idx = (blockIdx.x - 1) * 256 + threadIdx.x;   // 0..65535
        int c = idx >> 8;
        int k = idx & 255;
        int key = c >> 7, j = c & 127;
        float f = W1[(size_t)key * FEAT * HID + (size_t)k * HID + j];
        unsigned u = __float_as_uint(f);
        unsigned r = (u + 0x7FFFu + ((u >> 16) & 1u)) >> 16;   // RNE to bf16
        Bp[(size_t)c * FEAT + k] = (unsigned short)r;
        return;
    }
    for (int i = threadIdx.x; i < out_n; i += 256) out[i] = 0.0f;

    __shared__ long long tsum[256];
    __shared__ int csum[256];
    int tid = threadIdx.x;
    const int* a32 = (const int*)num_atoms_raw;
    const long long* a64 = (const long long*)num_atoms_raw;
    int chunk = (n_mols + 255) >> 8;
    int lo = tid * chunk;
    if (lo > n_mols) lo = n_mols;
    int hi = lo + chunk;
    if (hi > n_mols) hi = n_mols;

    long long s32 = 0;
    for (int i = lo; i < hi; ++i) s32 += (long long)a32[i];
    tsum[tid] = s32;
    __syncthreads();
    #pragma unroll
    for (int d = 128; d > 0; d >>= 1) {
        if (tid < d) tsum[tid] += tsum[tid + d];
        __syncthreads();
    }
    int mode = (tsum[0] == (long long)n_atoms) ? 0 : 1;
    long long s = s32;
    if (mode) {
        s = 0;
        for (int i = lo; i < hi; ++i) s += a64[i];
    }
    int v = (int)s;
    csum[tid] = v;
    __syncthreads();
    #pragma unroll
    for (int d = 1; d < 256; d <<= 1) {
        int t = (tid >= d) ? csum[tid - d] : 0;
        __syncthreads();
        csum[tid] += t;
        __syncthreads();
    }
    int run = csum[tid] - v;
    for (int i = lo; i < hi; ++i) {
        off[i] = run;
        run += mode ? (int)a64[i] : a32[i];
    }
    if (hi >= n_mols) off[n_mols] = run;
}

// Persistent-block fused GEMM + MLP epilogue + segment-sum.
// 512 threads = 8 waves; wave w owns output cols [w*32, w*32+32) (key = w>>2).
// Tile = 64 rows; K in 4 chunks of 64. 3-buffer, 2-chunk-ahead DMA pipeline:
//   per chunk: [barrier] -> bw loads -> DMA(chunk+2) -> compute.
// Barriers carry NO vmcnt drain (bar_raw / bar_lds), so DMAs stay in flight
// across them; the compiler's wait-for-bw (vmcnt(2), in-order retirement)
// retires DMA(c+1) -- one full chunk-time old -- while DMA(c+2) rides through
// compute. No hand vmcnt in the loop -> compiler-tracked correctness.
// c==0 uses bar_lds (lgkm-only drain): retires the previous tile's epilogue
// flush-READS before this tile's rowmol WRITE (cross-tile LDS WAR race).
// Compute sequences row0-read/pack/MFMA then row1 to halve peak liveness
// (anti-spill: rounds 3/4 showed 34MB of scratch-suspect HBM writes).
__global__ __launch_bounds__(512, 4)
void gemm_fused(const float* __restrict__ A,
                const unsigned short* __restrict__ Bp,
                const float* __restrict__ b1,
                const float* __restrict__ W2,
                const float* __restrict__ b2,
                const int* __restrict__ off,
                float* __restrict__ out,
                int n_atoms, int n_mols, int ntiles, int stride) {
    __shared__ uint4  ldsA[3][1024];      // 3 x 16KB A-chunk (64 rows x 16 units)
    __shared__ int    offlds[2048];       // 8KB prefix offsets
    __shared__ float  part[8][64];        // [wave][row]
    __shared__ int    rowmol[64];
    __shared__ float  molacc[NKEYS][4];

    const int tid  = threadIdx.x;
    const int lane = tid & 63;
    const int wid  = tid >> 6;            // 0..7
    const int l31  = lane & 31;
    const int half = lane >> 5;

    const bool lds_ok = (n_mols + 1) <= 2048;
    if (lds_ok) ((int4*)offlds)[tid] = ((const int4*)off)[tid];
    if (tid < NKEYS * 4) molacc[tid >> 2][tid & 3] = 0.0f;

    const int c0 = wid * 32 + l31;
    const unsigned short* bb = Bp + (size_t)c0 * FEAT + half * 8;
    const float b1c  = b1[c0];
    const float w2c  = W2[c0];
    const float b2k0 = b2[0], b2k1 = b2[1];
    const int rB = l31 + 32;
    const int x  = l31 & 15;

    // stage chunk (tile, cc) into ldsA[buf]: per thread 2 DMAs of 16B.
    // LDS unit (row r, u) holds source unit u ^ (r&15) (involution; the read
    // side applies the same XOR). DMA dest is linear (rule #21).
    auto stage = [&](int tile, int cc, int buf) {
        const int m0s = tile * 64;
        #pragma unroll
        for (int i = 0; i < 2; ++i) {
            const int pos = wid * 128 + i * 64;        // wave-uniform dest unit
            const int r   = (pos >> 4) + (lane >> 4);  // this lane's row
            const int u   = (lane & 15) ^ (r & 15);    // inverse-swizzled src
            int gr = m0s + r;
            if (gr > n_atoms - 1) gr = n_atoms - 1;
            gload_lds16(A + (size_t)gr * FEAT + cc * 64 + u * 4,
                        (void*)(&ldsA[buf][pos]));
        }
    };

    int t = blockIdx.x;
    stage(t, 0, 0);
    stage(t, 1, 1);
    __syncthreads();      // startup only: full drain is fine here

    int cur = 0;          // buffer holding the current chunk
    for (; t < ntiles; t += stride) {
        const int m0 = t * 64;
        f32x16 acc0 = 0.0f, acc1 = 0.0f;

        #pragma unroll
        for (int c = 0; c < 4; ++c) {
            // all waves' DMA(c) retired (each wave retired its own during the
            // previous chunk's bw-wait); barrier publishes LDS + protects the
            // buffer DMA(c+2) will overwrite (last read 3 chunks ago).
            // c==0: lgkm-drain variant (cross-tile epilogue-read WAR fix).
            if (c == 0) bar_lds(); else bar_raw();

            // B frags FIRST: compiler waits vmcnt(2) for these before the
            // MFMAs, leaving DMA(c+2) in flight (in-order vmcnt retirement).
            Frag bw[4];
            #pragma unroll
            for (int j = 0; j < 4; ++j)
                bw[j].q = *(const uint4*)(bb + c * 64 + j * 16);
            __builtin_amdgcn_sched_barrier(0);

            // issue DMA for chunk c+2 (2-deep pipeline)
            {
                const int t2 = (c < 2) ? t : (t + stride);
                if (t2 < ntiles) {
                    int nb = cur + 2; if (nb >= 3) nb -= 3;
                    stage(t2, (c + 2) & 3, nb);
                }
            }
            __builtin_amdgcn_sched_barrier(0);

            // per-tile row->mol map, one search per 8 threads
            if (c == 0 && (tid & 7) == 0) {
                int r = tid >> 3;
                int gm = m0 + r;
                if (gm > n_atoms - 1) gm = n_atoms - 1;
                rowmol[r] = lds_ok ? find_mol(offlds, n_mols, gm)
                                   : find_mol(off, n_mols, gm);
            }

            // compute current chunk; row0 then row1 to halve temp liveness
            const uint4* lbuf = &ldsA[cur][0];
            #pragma unroll
            for (int ks = 0; ks < 4; ++ks) {
                const int us = (ks * 4 + half * 2) ^ x;
                {
                    uint4 lo = lbuf[l31 * 16 + us];
                    uint4 hi = lbuf[l31 * 16 + (us ^ 1)];
                    const float4 fl = *(const float4*)&lo;
                    const float4 fh = *(const float4*)&hi;
                    Frag a0;
                    a0.u[0] = pack_bf16_2(fl.x, fl.y);
                    a0.u[1] = pack_bf16_2(fl.z, fl.w);
                    a0.u[2] = pack_bf16_2(fh.x, fh.y);
                    a0.u[3] = pack_bf16_2(fh.z, fh.w);
                    acc0 = __builtin_amdgcn_mfma_f32_32x32x16_bf16(a0.v, bw[ks].v, acc0, 0, 0, 0);
                }
                {
                    uint4 lo = lbuf[rB * 16 + us];
                    uint4 hi = lbuf[rB * 16 + (us ^ 1)];
                    const float4 fl = *(const float4*)&lo;
                    const float4 fh = *(const float4*)&hi;
                    Frag a1;
                    a1.u[0] = pack_bf16_2(fl.x, fl.y);
                    a1.u[1] = pack_bf16_2(fl.z, fl.w);
                    a1.u[2] = pack_bf16_2(fh.x, fh.y);
                    a1.u[3] = pack_bf16_2(fh.z, fh.w);
                    acc1 = __builtin_amdgcn_mfma_f32_32x32x16_bf16(a1.v, bw[ks].v, acc1, 0, 0, 0);
                }
            }
            cur = (cur >= 2) ? 0 : cur + 1;
        }

        // ---- epilogue (once per tile): act + .W2, reduce 32 cols per row
        #pragma unroll
        for (int rt = 0; rt < 2; ++rt) {
            const f32x16& Ac = rt ? acc1 : acc0;
            #pragma unroll
            for (int r = 0; r < 16; ++r) {
                float v = ssp(Ac[r] + b1c) * w2c;
                v += __shfl_xor(v, 1);
                v += __shfl_xor(v, 2);
                v += __shfl_xor(v, 4);
                v += __shfl_xor(v, 8);
                v += __shfl_xor(v, 16);
                if (l31 == r) {
                    int row = rt * 32 + (r & 3) + 8 * (r >> 2) + 4 * half;
                    part[wid][row] = v;
                }
            }
        }
        bar_lds();   // publish part[] (lgkm only; DMAs stay in flight)

        if (tid < NKEYS * 64) {
            int k = tid >> 6, r = tid & 63;
            int gm = m0 + r;
            if (gm < n_atoms) {
                float val = part[4 * k][r] + part[4 * k + 1][r]
                          + part[4 * k + 2][r] + part[4 * k + 3][r]
                          + (k ? b2k1 : b2k0);
                int mol = rowmol[r];
                int ml  = mol - rowmol[0];
                if (ml < 4) atomicAdd(&molacc[k][ml], val);
                else        atomicAdd(&out[(size_t)k * n_mols + mol], val);
            }
        }
        bar_lds();   // publish molacc

        if (tid < NKEYS * 4) {
            int k = tid >> 2, ml = tid & 3;
            int mol = rowmol[0] + ml;
            if (mol < n_mols) {
                float v = molacc[k][ml];
                if (v != 0.0f) atomicAdd(&out[(size_t)k * n_mols + mol], v);
                molacc[k][ml] = 0.0f;
            }
        }
        // flush-READS above retire at the next tile's c==0 bar_lds before any
        // rewrite of rowmol/molacc (writes happen after that barrier).
    }
}

extern "C" void kernel_launch(void* const* d_in, const int* in_sizes, int n_in,
                              void* d_out, int out_size, void* d_ws, size_t ws_size,
                              hipStream_t stream) {
    const float* s_i      = (const float*)d_in[0];
    // d_in[1] = xyz: unused by the reference output
    const void*  num_atoms = d_in[2];
    const float* W1 = (const float*)d_in[3];
    const float* b1 = (const float*)d_in[4];
    const float* W2 = (const float*)d_in[5];
    const float* b2 = (const float*)d_in[6];
    int n_atoms = in_sizes[0] / FEAT;
    int n_mols  = in_sizes[2];
    float* out = (float*)d_out;

    int* off = (int*)d_ws;
    size_t off_bytes = (((size_t)(n_mols + 1) * 4) + 255) & ~(size_t)255;
    if (off_bytes < 8192) off_bytes = 8192;   // gemm_fused reads 8KB of off
    unsigned short* Bp = (unsigned short*)((char*)d_ws + off_bytes);

    int pack_blocks = (NKEYS * HID * FEAT) / 256;   // 256
    prep_kernel<<<1 + pack_blocks, 256, 0, stream>>>(num_atoms, W1, n_mols, n_atoms,
                                                     off, Bp, out, out_size);

    int ntiles  = (n_atoms + 63) / 64;
    int nblocks = ntiles < 512 ? ntiles : 512;
    gemm_fused<<<nblocks, 512, 0, stream>>>(s_i, Bp, b1, W2, b2, off, out,
                                            n_atoms, n_mols, ntiles, nblocks);
}